// Round 1
// baseline (742.070 us; speedup 1.0000x reference)
//
#include <hip/hip_runtime.h>

// RGCN 2-layer fused implementation for MI355X.
// Strategy: build dst-CSR once (graph identical across layers), then each
// layer = ONE fused kernel (edge aggregate + self-loop matvec + norms + relu),
// one wave (64 lanes) per node, lane = feature column. No float atomics.

#define SCAN_BLK 1024

__global__ void deg_kernel(const int* __restrict__ src, const int* __restrict__ dst,
                           int* __restrict__ out_cnt, int* __restrict__ in_cnt, int E) {
  int i = blockIdx.x * blockDim.x + threadIdx.x;
  int stride = gridDim.x * blockDim.x;
  for (int e = i; e < E; e += stride) {
    atomicAdd(&out_cnt[src[e]], 1);
    atomicAdd(&in_cnt[dst[e]], 1);
  }
}

// Per-block inclusive scan of in_cnt -> rowptr[i+1]; block sums out.
__global__ void scan_a(const int* __restrict__ in, int* __restrict__ out1,
                       int* __restrict__ bsums, int n) {
  __shared__ int tmp[SCAN_BLK];
  int i = blockIdx.x * SCAN_BLK + threadIdx.x;
  tmp[threadIdx.x] = (i < n) ? in[i] : 0;
  __syncthreads();
  for (int off = 1; off < SCAN_BLK; off <<= 1) {
    int t = (threadIdx.x >= off) ? tmp[threadIdx.x - off] : 0;
    __syncthreads();
    tmp[threadIdx.x] += t;
    __syncthreads();
  }
  if (i < n) out1[i] = tmp[threadIdx.x];          // rowptr[i+1], block-local
  if (threadIdx.x == SCAN_BLK - 1) bsums[blockIdx.x] = tmp[SCAN_BLK - 1];
}

__global__ void scan_b(const int* __restrict__ bsums, int* __restrict__ boff, int nb) {
  if (blockIdx.x == 0 && threadIdx.x == 0) {
    int run = 0;
    for (int b = 0; b < nb; ++b) { boff[b] = run; run += bsums[b]; }
  }
}

__global__ void scan_c(int* __restrict__ rowptr, const int* __restrict__ boff, int n) {
  int i = blockIdx.x * blockDim.x + threadIdx.x;
  if (i < n) rowptr[i + 1] += boff[i >> 10];
  if (i == 0) rowptr[0] = 0;
}

__global__ void norms_cursor_kernel(const int* __restrict__ out_cnt, const int* __restrict__ in_cnt,
                                    const int* __restrict__ rowptr,
                                    float* __restrict__ norm_out, float* __restrict__ inv_in,
                                    float* __restrict__ norm_in, int* __restrict__ cursor, int n) {
  int i = blockIdx.x * blockDim.x + threadIdx.x;
  if (i < n) {
    float od = (float)max(out_cnt[i], 1);
    float id = (float)max(in_cnt[i], 1);
    norm_out[i] = rsqrtf(od);
    inv_in[i]   = 1.0f / id;
    norm_in[i]  = rsqrtf(id);
    cursor[i]   = rowptr[i];
  }
}

__global__ void fill_csr(const int* __restrict__ src, const int* __restrict__ dst,
                         const int* __restrict__ et, int* __restrict__ cursor,
                         int* __restrict__ csrc, int* __restrict__ cet, int E) {
  int i = blockIdx.x * blockDim.x + threadIdx.x;
  int stride = gridDim.x * blockDim.x;
  for (int e = i; e < E; e += stride) {
    int d = dst[e];
    int pos = atomicAdd(&cursor[d], 1);
    csrc[pos] = src[e];
    cet[pos]  = et[e];
  }
}

// Fused RGCN layer: one wave per node, lane = column.
// xout[n,c] = relu( (sum_k xin[n,k]*W[k,c]
//                    + inv_in[n] * sum_{e in CSR[n]} xin[s_e,c]*norm_out[s_e]*relw[t_e,c])
//                   * norm_in[n] )
__launch_bounds__(256, 4)
__global__ void layer_kernel(const float* __restrict__ xin, const float* __restrict__ W,
                             const float* __restrict__ relw,
                             const int* __restrict__ rowptr, const int* __restrict__ csrc,
                             const int* __restrict__ cet,
                             const float* __restrict__ norm_out, const float* __restrict__ inv_in,
                             const float* __restrict__ norm_in,
                             float* __restrict__ xout, int n) {
  __shared__ float Wl[64][64];   // 16 KB; Wl[k][lane]: bank = lane%32 -> 2-way (free)
  for (int i = threadIdx.x; i < 64 * 64; i += blockDim.x) Wl[i >> 6][i & 63] = W[i];
  __syncthreads();

  const int lane   = threadIdx.x & 63;
  const int wid    = (blockIdx.x * blockDim.x + threadIdx.x) >> 6;
  const int nwaves = (gridDim.x * blockDim.x) >> 6;

  for (int node = wid; node < n; node += nwaves) {
    // ---- edge aggregation (coalesced 256B row gathers, no atomics) ----
    float acc = 0.f;
    const int e1 = rowptr[node + 1];
    for (int e = rowptr[node]; e < e1; ++e) {
      const int s = csrc[e];
      const int t = cet[e];
      acc += xin[(size_t)s * 64 + lane] * norm_out[s] * relw[t * 64 + lane];
    }
    const float mix = acc * inv_in[node];

    // ---- self-loop matvec: dot(xin[node,:], W[:,lane]) via LDS W ----
    float dense = 0.f;
    const float4* xr = reinterpret_cast<const float4*>(xin + (size_t)node * 64);
#pragma unroll
    for (int k4 = 0; k4 < 16; ++k4) {
      const float4 v = xr[k4];
      const int k = k4 * 4;
      dense = fmaf(v.x, Wl[k][lane],
              fmaf(v.y, Wl[k + 1][lane],
              fmaf(v.z, Wl[k + 2][lane],
              fmaf(v.w, Wl[k + 3][lane], dense))));
    }

    const float r = (dense + mix) * norm_in[node];
    xout[(size_t)node * 64 + lane] = fmaxf(r, 0.f);
  }
}

extern "C" void kernel_launch(void* const* d_in, const int* in_sizes, int n_in,
                              void* d_out, int out_size, void* d_ws, size_t ws_size,
                              hipStream_t stream) {
  const float* x     = (const float*)d_in[0];
  const float* relw  = (const float*)d_in[1];
  const float* w1    = (const float*)d_in[2];
  const float* w2    = (const float*)d_in[3];
  const int*   src   = (const int*)d_in[4];
  const int*   dst   = (const int*)d_in[5];
  const int*   etype = (const int*)d_in[6];

  const int N = in_sizes[0] / 64;
  const int E = in_sizes[4];

  // ---- workspace carve-up (256B aligned) ----
  char* w = (char*)d_ws;
  size_t off = 0;
  auto alloc = [&](size_t bytes) -> void* {
    void* p = w + off;
    off = (off + bytes + 255) & ~(size_t)255;
    return p;
  };
  int* out_cnt   = (int*)alloc((size_t)N * 4);      // zeroed below (adjacent with in_cnt)
  int* in_cnt    = (int*)alloc((size_t)N * 4);
  int* rowptr    = (int*)alloc((size_t)(N + 1) * 4);
  int* cursor    = (int*)alloc((size_t)N * 4);
  float* norm_out= (float*)alloc((size_t)N * 4);
  float* inv_in  = (float*)alloc((size_t)N * 4);
  float* norm_in = (float*)alloc((size_t)N * 4);
  int* bsums     = (int*)alloc(256 * 4);
  int* boff      = (int*)alloc(256 * 4);
  int* csrc      = (int*)alloc((size_t)E * 4);
  int* cet       = (int*)alloc((size_t)E * 4);
  float* h       = (float*)alloc((size_t)N * 64 * 4);

  // zero the two degree count arrays (they are contiguous in ws)
  hipMemsetAsync(out_cnt, 0, ((char*)rowptr - (char*)out_cnt), stream);

  const int nb = (N + SCAN_BLK - 1) / SCAN_BLK;

  deg_kernel<<<4096, 256, 0, stream>>>(src, dst, out_cnt, in_cnt, E);
  scan_a<<<nb, SCAN_BLK, 0, stream>>>(in_cnt, rowptr + 1, bsums, N);
  scan_b<<<1, 64, 0, stream>>>(bsums, boff, nb);
  scan_c<<<(N + 255) / 256, 256, 0, stream>>>(rowptr, boff, N);
  norms_cursor_kernel<<<(N + 255) / 256, 256, 0, stream>>>(out_cnt, in_cnt, rowptr,
                                                           norm_out, inv_in, norm_in, cursor, N);
  fill_csr<<<4096, 256, 0, stream>>>(src, dst, etype, cursor, csrc, cet, E);

  // layer 1: x -> h (with w1), layer 2: h -> out (with w2)
  layer_kernel<<<2048, 256, 0, stream>>>(x, w1, relw, rowptr, csrc, cet,
                                         norm_out, inv_in, norm_in, h, N);
  layer_kernel<<<2048, 256, 0, stream>>>(h, w2, relw, rowptr, csrc, cet,
                                         norm_out, inv_in, norm_in, (float*)d_out, N);
}

// Round 4
// 484.348 us; speedup vs baseline: 1.5321x; 1.5321x over previous
//
#include <hip/hip_runtime.h>

// RGCN 2-layer fused, MI355X. dst-CSR built once per call; each layer is one
// fused kernel: wave = 1 node, 4 groups x 16 lanes, lane = 4 columns (float4).
// Edge metadata packed (src | etype<<20). Features kept pre-scaled by
// norm_out; dense self-loop reconstructed via sq_out. No float atomics.

#define SCAN_BLK 1024

__global__ void deg_kernel(const int* __restrict__ src, const int* __restrict__ dst,
                           int* __restrict__ out_cnt, int* __restrict__ in_cnt, int E) {
  int i = blockIdx.x * blockDim.x + threadIdx.x;
  int stride = gridDim.x * blockDim.x;
  for (int e = i; e < E; e += stride) {
    atomicAdd(&out_cnt[src[e]], 1);
    atomicAdd(&in_cnt[dst[e]], 1);
  }
}

// Per-block inclusive scan of in_cnt -> rowptr[i+1] (block-local); block sums out.
__global__ void scan_a(const int* __restrict__ in, int* __restrict__ out1,
                       int* __restrict__ bsums, int n) {
  __shared__ int tmp[SCAN_BLK];
  int i = blockIdx.x * SCAN_BLK + threadIdx.x;
  tmp[threadIdx.x] = (i < n) ? in[i] : 0;
  __syncthreads();
  for (int off = 1; off < SCAN_BLK; off <<= 1) {
    int t = (threadIdx.x >= off) ? tmp[threadIdx.x - off] : 0;
    __syncthreads();
    tmp[threadIdx.x] += t;
    __syncthreads();
  }
  if (i < n) out1[i] = tmp[threadIdx.x];
  if (threadIdx.x == SCAN_BLK - 1) bsums[blockIdx.x] = tmp[SCAN_BLK - 1];
}

// Parallel exclusive scan of block sums (nb <= 256), single block.
__global__ void scan_b(const int* __restrict__ bsums, int* __restrict__ boff, int nb) {
  __shared__ int t[256];
  int v = (threadIdx.x < nb) ? bsums[threadIdx.x] : 0;
  t[threadIdx.x] = v;
  __syncthreads();
  for (int off = 1; off < 256; off <<= 1) {
    int u = (threadIdx.x >= off) ? t[threadIdx.x - off] : 0;
    __syncthreads();
    t[threadIdx.x] += u;
    __syncthreads();
  }
  if (threadIdx.x < nb) boff[threadIdx.x] = t[threadIdx.x] - v;  // exclusive
}

__global__ void scan_c(int* __restrict__ rowptr, const int* __restrict__ boff, int n) {
  int i = blockIdx.x * blockDim.x + threadIdx.x;
  if (i < n) rowptr[i + 1] += boff[i >> 10];
  if (i == 0) rowptr[0] = 0;
}

// nrm4[i] = {inv_in, sq_out, norm_in, norm_out}
__global__ void norms_kernel(const int* __restrict__ out_cnt, const int* __restrict__ in_cnt,
                             const int* __restrict__ rowptr,
                             float4* __restrict__ nrm4, int* __restrict__ cursor, int n) {
  int i = blockIdx.x * blockDim.x + threadIdx.x;
  if (i < n) {
    float od = (float)max(out_cnt[i], 1);
    float id = (float)max(in_cnt[i], 1);
    float4 v;
    v.x = 1.0f / id;      // inv_in
    v.y = sqrtf(od);      // sq_out  (undoes norm_out for the self-loop term)
    v.z = rsqrtf(id);     // norm_in
    v.w = rsqrtf(od);     // norm_out
    nrm4[i] = v;
    cursor[i] = rowptr[i];
  }
}

// xs = x * norm_out (row-wise)
__global__ void prescale_kernel(const float4* __restrict__ x4, const float4* __restrict__ nrm4,
                                float4* __restrict__ xs4, int n16) {
  int i = blockIdx.x * blockDim.x + threadIdx.x;
  if (i < n16) {
    float no = nrm4[i >> 4].w;
    float4 v = x4[i];
    v.x *= no; v.y *= no; v.z *= no; v.w *= no;
    xs4[i] = v;
  }
}

__global__ void fill_csr(const int* __restrict__ src, const int* __restrict__ dst,
                         const int* __restrict__ et, int* __restrict__ cursor,
                         int* __restrict__ ce, int E) {
  int i = blockIdx.x * blockDim.x + threadIdx.x;
  int stride = gridDim.x * blockDim.x;
  for (int e = i; e < E; e += stride) {
    int d = dst[e];
    int pos = atomicAdd(&cursor[d], 1);
    ce[pos] = src[e] | (et[e] << 20);   // src < 2^17, etype < 2^6
  }
}

// Fused RGCN layer. Wave = 1 node. Groups g=0..3 (16 lanes each), lane owns
// 4 columns c = 4*l .. 4*l+3. Edges strided by group; dense k interleaved
// (k = 4*kk + g). Combine with 2 rounds of shfl_xor.
#define WSTRIDE 68  // LDS row stride in floats: conflict-free b128 w/ k%4 groups
template <bool FINAL>
__launch_bounds__(256, 6)
__global__ void layer_kernel(const float* __restrict__ xs, const float* __restrict__ W,
                             const float* __restrict__ relw,
                             const int* __restrict__ rowptr, const int* __restrict__ ce,
                             const float4* __restrict__ nrm4,
                             float* __restrict__ xout, int n) {
  __shared__ float Wl[64 * WSTRIDE];
  for (int i = threadIdx.x; i < 64 * 64; i += 256)
    Wl[(i >> 6) * WSTRIDE + (i & 63)] = W[i];
  __syncthreads();

  const int node = blockIdx.x * 4 + (threadIdx.x >> 6);
  if (node >= n) return;
  const int lane = threadIdx.x & 63;
  const int g = lane >> 4;
  const int l = lane & 15;

  const int rb = rowptr[node];
  const int re = rowptr[node + 1];
  const float4 nr = nrm4[node];  // {inv_in, sq_out, norm_in, norm_out}

  const float4* __restrict__ xs4 = (const float4*)xs;
  const float4* __restrict__ rw4 = (const float4*)relw;

  // ---- edge aggregation: group g takes edges rb+g, rb+g+4, ... ----
  float4 acc = {0.f, 0.f, 0.f, 0.f};
  for (int e = rb + g; e < re; e += 4) {
    const int p = ce[e];
    const int s = p & 0xFFFFF;
    const int t = p >> 20;
    const float4 xv = xs4[(size_t)s * 16 + l];
    const float4 rv = rw4[t * 16 + l];
    acc.x = fmaf(xv.x, rv.x, acc.x);
    acc.y = fmaf(xv.y, rv.y, acc.y);
    acc.z = fmaf(xv.z, rv.z, acc.z);
    acc.w = fmaf(xv.w, rv.w, acc.w);
  }

  // ---- dense self-loop: group g covers k = 4*kk + g ----
  float4 d = {0.f, 0.f, 0.f, 0.f};
  const float* __restrict__ xrow = xs + (size_t)node * 64;
#pragma unroll 4
  for (int kk = 0; kk < 16; ++kk) {
    const int k = (kk << 2) + g;
    const float xk = xrow[k];
    const float4 w4 = *(const float4*)&Wl[k * WSTRIDE + (l << 2)];
    d.x = fmaf(xk, w4.x, d.x);
    d.y = fmaf(xk, w4.y, d.y);
    d.z = fmaf(xk, w4.z, d.z);
    d.w = fmaf(xk, w4.w, d.w);
  }

  // per-group partial with uniform scalars folded in (distributes over sum)
  float4 pre;
  pre.x = fmaf(acc.x, nr.x, d.x * nr.y);
  pre.y = fmaf(acc.y, nr.x, d.y * nr.y);
  pre.z = fmaf(acc.z, nr.x, d.z * nr.y);
  pre.w = fmaf(acc.w, nr.x, d.w * nr.y);

  // reduce across the 4 groups
  pre.x += __shfl_xor(pre.x, 16); pre.x += __shfl_xor(pre.x, 32);
  pre.y += __shfl_xor(pre.y, 16); pre.y += __shfl_xor(pre.y, 32);
  pre.z += __shfl_xor(pre.z, 16); pre.z += __shfl_xor(pre.z, 32);
  pre.w += __shfl_xor(pre.w, 16); pre.w += __shfl_xor(pre.w, 32);

  if (g == 0) {
    // relu(a)*c == relu(a*c) for c>0, so fold norm_in (and norm_out if !FINAL)
    const float scale = FINAL ? nr.z : nr.z * nr.w;
    float4 o;
    o.x = fmaxf(pre.x * scale, 0.f);
    o.y = fmaxf(pre.y * scale, 0.f);
    o.z = fmaxf(pre.z * scale, 0.f);
    o.w = fmaxf(pre.w * scale, 0.f);
    ((float4*)xout)[(size_t)node * 16 + l] = o;
  }
}

extern "C" void kernel_launch(void* const* d_in, const int* in_sizes, int n_in,
                              void* d_out, int out_size, void* d_ws, size_t ws_size,
                              hipStream_t stream) {
  const float* x     = (const float*)d_in[0];
  const float* relw  = (const float*)d_in[1];
  const float* w1    = (const float*)d_in[2];
  const float* w2    = (const float*)d_in[3];
  const int*   src   = (const int*)d_in[4];
  const int*   dst   = (const int*)d_in[5];
  const int*   etype = (const int*)d_in[6];

  const int N = in_sizes[0] / 64;
  const int E = in_sizes[4];

  char* w = (char*)d_ws;
  size_t off = 0;
  auto alloc = [&](size_t bytes) -> void* {
    void* p = w + off;
    off = (off + bytes + 255) & ~(size_t)255;
    return p;
  };
  int*    out_cnt = (int*)alloc((size_t)N * 4);     // zeroed (contiguous with in_cnt)
  int*    in_cnt  = (int*)alloc((size_t)N * 4);
  int*    rowptr  = (int*)alloc((size_t)(N + 1) * 4);
  int*    cursor  = (int*)alloc((size_t)N * 4);
  float4* nrm4    = (float4*)alloc((size_t)N * 16);
  int*    bsums   = (int*)alloc(256 * 4);
  int*    boff    = (int*)alloc(256 * 4);
  int*    ce      = (int*)alloc((size_t)E * 4);     // packed src|etype<<20
  float*  xs      = (float*)alloc((size_t)N * 64 * 4);  // prescaled layer-1 input
  float*  h1s     = (float*)alloc((size_t)N * 64 * 4);  // prescaled layer-1 output

  // zero the two degree arrays (contiguous in ws)
  hipMemsetAsync(out_cnt, 0, ((char*)rowptr - (char*)out_cnt), stream);

  const int nb = (N + SCAN_BLK - 1) / SCAN_BLK;

  deg_kernel<<<4096, 256, 0, stream>>>(src, dst, out_cnt, in_cnt, E);
  scan_a<<<nb, SCAN_BLK, 0, stream>>>(in_cnt, rowptr + 1, bsums, N);
  scan_b<<<1, 256, 0, stream>>>(bsums, boff, nb);
  scan_c<<<(N + 255) / 256, 256, 0, stream>>>(rowptr, boff, N);
  norms_kernel<<<(N + 255) / 256, 256, 0, stream>>>(out_cnt, in_cnt, rowptr, nrm4, cursor, N);
  prescale_kernel<<<(N * 16 + 255) / 256, 256, 0, stream>>>((const float4*)x, nrm4,
                                                            (float4*)xs, N * 16);
  fill_csr<<<4096, 256, 0, stream>>>(src, dst, etype, cursor, ce, E);

  const int lblocks = (N + 3) / 4;
  layer_kernel<false><<<lblocks, 256, 0, stream>>>(xs, w1, relw, rowptr, ce, nrm4, h1s, N);
  layer_kernel<true><<<lblocks, 256, 0, stream>>>(h1s, w2, relw, rowptr, ce, nrm4,
                                                  (float*)d_out, N);
}

// Round 5
// 467.476 us; speedup vs baseline: 1.5874x; 1.0361x over previous
//
#include <hip/hip_runtime.h>

// RGCN 2-layer fused, MI355X. dst-CSR built once per call; each layer is one
// fused kernel: wave = 1 node, 4 groups x 16 lanes, lane = 4 columns (float4).
// Edge metadata packed (src | etype<<20). Features kept pre-scaled by
// norm_out; dense self-loop reconstructed via sq_out. No float atomics.
// R4: no LDS (W read from L1-resident global), edge loop unrolled x2 for MLP.

#define SCAN_BLK 1024

__global__ void deg_kernel(const int* __restrict__ src, const int* __restrict__ dst,
                           int* __restrict__ out_cnt, int* __restrict__ in_cnt, int E) {
  int i = blockIdx.x * blockDim.x + threadIdx.x;
  int stride = gridDim.x * blockDim.x;
  for (int e = i; e < E; e += stride) {
    atomicAdd(&out_cnt[src[e]], 1);
    atomicAdd(&in_cnt[dst[e]], 1);
  }
}

// Per-block inclusive scan of in_cnt -> rowptr[i+1] (block-local); block sums out.
__global__ void scan_a(const int* __restrict__ in, int* __restrict__ out1,
                       int* __restrict__ bsums, int n) {
  __shared__ int tmp[SCAN_BLK];
  int i = blockIdx.x * SCAN_BLK + threadIdx.x;
  tmp[threadIdx.x] = (i < n) ? in[i] : 0;
  __syncthreads();
  for (int off = 1; off < SCAN_BLK; off <<= 1) {
    int t = (threadIdx.x >= off) ? tmp[threadIdx.x - off] : 0;
    __syncthreads();
    tmp[threadIdx.x] += t;
    __syncthreads();
  }
  if (i < n) out1[i] = tmp[threadIdx.x];
  if (threadIdx.x == SCAN_BLK - 1) bsums[blockIdx.x] = tmp[SCAN_BLK - 1];
}

// Parallel exclusive scan of block sums (nb <= 256), single block.
__global__ void scan_b(const int* __restrict__ bsums, int* __restrict__ boff, int nb) {
  __shared__ int t[256];
  int v = (threadIdx.x < nb) ? bsums[threadIdx.x] : 0;
  t[threadIdx.x] = v;
  __syncthreads();
  for (int off = 1; off < 256; off <<= 1) {
    int u = (threadIdx.x >= off) ? t[threadIdx.x - off] : 0;
    __syncthreads();
    t[threadIdx.x] += u;
    __syncthreads();
  }
  if (threadIdx.x < nb) boff[threadIdx.x] = t[threadIdx.x] - v;  // exclusive
}

__global__ void scan_c(int* __restrict__ rowptr, const int* __restrict__ boff, int n) {
  int i = blockIdx.x * blockDim.x + threadIdx.x;
  if (i < n) rowptr[i + 1] += boff[i >> 10];
  if (i == 0) rowptr[0] = 0;
}

// nrm4[i] = {inv_in, sq_out, norm_in, norm_out}
__global__ void norms_kernel(const int* __restrict__ out_cnt, const int* __restrict__ in_cnt,
                             const int* __restrict__ rowptr,
                             float4* __restrict__ nrm4, int* __restrict__ cursor, int n) {
  int i = blockIdx.x * blockDim.x + threadIdx.x;
  if (i < n) {
    float od = (float)max(out_cnt[i], 1);
    float id = (float)max(in_cnt[i], 1);
    float4 v;
    v.x = 1.0f / id;      // inv_in
    v.y = sqrtf(od);      // sq_out  (undoes norm_out for the self-loop term)
    v.z = rsqrtf(id);     // norm_in
    v.w = rsqrtf(od);     // norm_out
    nrm4[i] = v;
    cursor[i] = rowptr[i];
  }
}

// xs = x * norm_out (row-wise)
__global__ void prescale_kernel(const float4* __restrict__ x4, const float4* __restrict__ nrm4,
                                float4* __restrict__ xs4, int n16) {
  int i = blockIdx.x * blockDim.x + threadIdx.x;
  if (i < n16) {
    float no = nrm4[i >> 4].w;
    float4 v = x4[i];
    v.x *= no; v.y *= no; v.z *= no; v.w *= no;
    xs4[i] = v;
  }
}

__global__ void fill_csr(const int* __restrict__ src, const int* __restrict__ dst,
                         const int* __restrict__ et, int* __restrict__ cursor,
                         int* __restrict__ ce, int E) {
  int i = blockIdx.x * blockDim.x + threadIdx.x;
  int stride = gridDim.x * blockDim.x;
  for (int e = i; e < E; e += stride) {
    int d = dst[e];
    int pos = atomicAdd(&cursor[d], 1);
    ce[pos] = src[e] | (et[e] << 20);   // src < 2^17, etype < 2^6
  }
}

// Fused RGCN layer. Wave = 1 node. Groups g=0..3 (16 lanes each), lane owns
// 4 columns c = 4*l .. 4*l+3. Group g takes edges rb+g, rb+g+4, ... with the
// loop unrolled x2 (two independent gather chains in flight per group).
// Dense self-loop reads W fragments straight from global (16 KB, L1-resident).
template <bool FINAL>
__launch_bounds__(256, 8)
__global__ void layer_kernel(const float* __restrict__ xs, const float* __restrict__ W,
                             const float* __restrict__ relw,
                             const int* __restrict__ rowptr, const int* __restrict__ ce,
                             const float4* __restrict__ nrm4,
                             float* __restrict__ xout, int n) {
  const int node = blockIdx.x * 4 + (threadIdx.x >> 6);
  if (node >= n) return;
  const int lane = threadIdx.x & 63;
  const int g = lane >> 4;
  const int l = lane & 15;

  const int rb = rowptr[node];
  const int re = rowptr[node + 1];
  const float4 nr = nrm4[node];  // {inv_in, sq_out, norm_in, norm_out}

  const float4* __restrict__ xs4 = (const float4*)xs;
  const float4* __restrict__ rw4 = (const float4*)relw;
  const float4* __restrict__ W4  = (const float4*)W;

  // ---- edge aggregation: group g takes edges rb+g, rb+g+4, ...; unroll x2 ----
  float4 acc0 = {0.f, 0.f, 0.f, 0.f};
  float4 acc1 = {0.f, 0.f, 0.f, 0.f};
  int e = rb + g;
  for (; e + 4 < re; e += 8) {
    const int p0 = ce[e];
    const int p1 = ce[e + 4];
    const int s0 = p0 & 0xFFFFF, t0 = p0 >> 20;
    const int s1 = p1 & 0xFFFFF, t1 = p1 >> 20;
    const float4 xv0 = xs4[(size_t)s0 * 16 + l];
    const float4 xv1 = xs4[(size_t)s1 * 16 + l];
    const float4 rv0 = rw4[t0 * 16 + l];
    const float4 rv1 = rw4[t1 * 16 + l];
    acc0.x = fmaf(xv0.x, rv0.x, acc0.x);
    acc0.y = fmaf(xv0.y, rv0.y, acc0.y);
    acc0.z = fmaf(xv0.z, rv0.z, acc0.z);
    acc0.w = fmaf(xv0.w, rv0.w, acc0.w);
    acc1.x = fmaf(xv1.x, rv1.x, acc1.x);
    acc1.y = fmaf(xv1.y, rv1.y, acc1.y);
    acc1.z = fmaf(xv1.z, rv1.z, acc1.z);
    acc1.w = fmaf(xv1.w, rv1.w, acc1.w);
  }
  if (e < re) {
    const int p = ce[e];
    const int s = p & 0xFFFFF, t = p >> 20;
    const float4 xv = xs4[(size_t)s * 16 + l];
    const float4 rv = rw4[t * 16 + l];
    acc0.x = fmaf(xv.x, rv.x, acc0.x);
    acc0.y = fmaf(xv.y, rv.y, acc0.y);
    acc0.z = fmaf(xv.z, rv.z, acc0.z);
    acc0.w = fmaf(xv.w, rv.w, acc0.w);
  }
  float4 acc;
  acc.x = acc0.x + acc1.x;
  acc.y = acc0.y + acc1.y;
  acc.z = acc0.z + acc1.z;
  acc.w = acc0.w + acc1.w;

  // ---- dense self-loop: group g covers k = 4*kk + g; W from L1 ----
  float4 d = {0.f, 0.f, 0.f, 0.f};
  const float* __restrict__ xrow = xs + (size_t)node * 64;
#pragma unroll 4
  for (int kk = 0; kk < 16; ++kk) {
    const int k = (kk << 2) + g;
    const float xk = xrow[k];
    const float4 w4 = W4[(k << 4) + l];
    d.x = fmaf(xk, w4.x, d.x);
    d.y = fmaf(xk, w4.y, d.y);
    d.z = fmaf(xk, w4.z, d.z);
    d.w = fmaf(xk, w4.w, d.w);
  }

  // per-group partial with uniform scalars folded in (distributes over sum)
  float4 pre;
  pre.x = fmaf(acc.x, nr.x, d.x * nr.y);
  pre.y = fmaf(acc.y, nr.x, d.y * nr.y);
  pre.z = fmaf(acc.z, nr.x, d.z * nr.y);
  pre.w = fmaf(acc.w, nr.x, d.w * nr.y);

  // reduce across the 4 groups
  pre.x += __shfl_xor(pre.x, 16); pre.x += __shfl_xor(pre.x, 32);
  pre.y += __shfl_xor(pre.y, 16); pre.y += __shfl_xor(pre.y, 32);
  pre.z += __shfl_xor(pre.z, 16); pre.z += __shfl_xor(pre.z, 32);
  pre.w += __shfl_xor(pre.w, 16); pre.w += __shfl_xor(pre.w, 32);

  if (g == 0) {
    // relu(a)*c == relu(a*c) for c>0, so fold norm_in (and norm_out if !FINAL)
    const float scale = FINAL ? nr.z : nr.z * nr.w;
    float4 o;
    o.x = fmaxf(pre.x * scale, 0.f);
    o.y = fmaxf(pre.y * scale, 0.f);
    o.z = fmaxf(pre.z * scale, 0.f);
    o.w = fmaxf(pre.w * scale, 0.f);
    ((float4*)xout)[(size_t)node * 16 + l] = o;
  }
}

extern "C" void kernel_launch(void* const* d_in, const int* in_sizes, int n_in,
                              void* d_out, int out_size, void* d_ws, size_t ws_size,
                              hipStream_t stream) {
  const float* x     = (const float*)d_in[0];
  const float* relw  = (const float*)d_in[1];
  const float* w1    = (const float*)d_in[2];
  const float* w2    = (const float*)d_in[3];
  const int*   src   = (const int*)d_in[4];
  const int*   dst   = (const int*)d_in[5];
  const int*   etype = (const int*)d_in[6];

  const int N = in_sizes[0] / 64;
  const int E = in_sizes[4];

  char* w = (char*)d_ws;
  size_t off = 0;
  auto alloc = [&](size_t bytes) -> void* {
    void* p = w + off;
    off = (off + bytes + 255) & ~(size_t)255;
    return p;
  };
  int*    out_cnt = (int*)alloc((size_t)N * 4);     // zeroed (contiguous with in_cnt)
  int*    in_cnt  = (int*)alloc((size_t)N * 4);
  int*    rowptr  = (int*)alloc((size_t)(N + 1) * 4);
  int*    cursor  = (int*)alloc((size_t)N * 4);
  float4* nrm4    = (float4*)alloc((size_t)N * 16);
  int*    bsums   = (int*)alloc(256 * 4);
  int*    boff    = (int*)alloc(256 * 4);
  int*    ce      = (int*)alloc((size_t)E * 4);     // packed src|etype<<20
  float*  xs      = (float*)alloc((size_t)N * 64 * 4);  // prescaled layer-1 input
  float*  h1s     = (float*)alloc((size_t)N * 64 * 4);  // prescaled layer-1 output

  // zero the two degree arrays (contiguous in ws)
  hipMemsetAsync(out_cnt, 0, ((char*)rowptr - (char*)out_cnt), stream);

  const int nb = (N + SCAN_BLK - 1) / SCAN_BLK;

  deg_kernel<<<4096, 256, 0, stream>>>(src, dst, out_cnt, in_cnt, E);
  scan_a<<<nb, SCAN_BLK, 0, stream>>>(in_cnt, rowptr + 1, bsums, N);
  scan_b<<<1, 256, 0, stream>>>(bsums, boff, nb);
  scan_c<<<(N + 255) / 256, 256, 0, stream>>>(rowptr, boff, N);
  norms_kernel<<<(N + 255) / 256, 256, 0, stream>>>(out_cnt, in_cnt, rowptr, nrm4, cursor, N);
  prescale_kernel<<<(N * 16 + 255) / 256, 256, 0, stream>>>((const float4*)x, nrm4,
                                                            (float4*)xs, N * 16);
  fill_csr<<<4096, 256, 0, stream>>>(src, dst, etype, cursor, ce, E);

  const int lblocks = (N + 3) / 4;
  layer_kernel<false><<<lblocks, 256, 0, stream>>>(xs, w1, relw, rowptr, ce, nrm4, h1s, N);
  layer_kernel<true><<<lblocks, 256, 0, stream>>>(h1s, w2, relw, rowptr, ce, nrm4,
                                                  (float*)d_out, N);
}

// Round 7
// 465.389 us; speedup vs baseline: 1.5945x; 1.0045x over previous
//
#include <hip/hip_runtime.h>

// RGCN 2-layer fused, MI355X. dst-CSR built once per call; each layer is one
// fused kernel: wave = 1 node. Edge phase: 4 groups x 16 lanes, lane = 4 cols
// (float4), unroll x2. Dense self-loop: W staged in LDS, row-broadcast b32
// reads (0-conflict pattern, measured r0), lane = 1 col. Features pre-scaled
// by norm_out; self-loop reconstructed via sq_out. No float atomics.

#define SCAN_BLK 1024

__global__ void deg_kernel(const int* __restrict__ src, const int* __restrict__ dst,
                           int* __restrict__ out_cnt, int* __restrict__ in_cnt, int E) {
  int i = blockIdx.x * blockDim.x + threadIdx.x;
  int stride = gridDim.x * blockDim.x;
  for (int e = i; e < E; e += stride) {
    atomicAdd(&out_cnt[src[e]], 1);
    atomicAdd(&in_cnt[dst[e]], 1);
  }
}

// Per-block inclusive scan of in_cnt -> rowptr[i+1] (block-local); block sums out.
__global__ void scan_a(const int* __restrict__ in, int* __restrict__ out1,
                       int* __restrict__ bsums, int n) {
  __shared__ int tmp[SCAN_BLK];
  int i = blockIdx.x * SCAN_BLK + threadIdx.x;
  tmp[threadIdx.x] = (i < n) ? in[i] : 0;
  __syncthreads();
  for (int off = 1; off < SCAN_BLK; off <<= 1) {
    int t = (threadIdx.x >= off) ? tmp[threadIdx.x - off] : 0;
    __syncthreads();
    tmp[threadIdx.x] += t;
    __syncthreads();
  }
  if (i < n) out1[i] = tmp[threadIdx.x];
  if (threadIdx.x == SCAN_BLK - 1) bsums[blockIdx.x] = tmp[SCAN_BLK - 1];
}

// Parallel exclusive scan of block sums (nb <= 256), single block.
__global__ void scan_b(const int* __restrict__ bsums, int* __restrict__ boff, int nb) {
  __shared__ int t[256];
  int v = (threadIdx.x < nb) ? bsums[threadIdx.x] : 0;
  t[threadIdx.x] = v;
  __syncthreads();
  for (int off = 1; off < 256; off <<= 1) {
    int u = (threadIdx.x >= off) ? t[threadIdx.x - off] : 0;
    __syncthreads();
    t[threadIdx.x] += u;
    __syncthreads();
  }
  if (threadIdx.x < nb) boff[threadIdx.x] = t[threadIdx.x] - v;  // exclusive
}

__global__ void scan_c(int* __restrict__ rowptr, const int* __restrict__ boff, int n) {
  int i = blockIdx.x * blockDim.x + threadIdx.x;
  if (i < n) rowptr[i + 1] += boff[i >> 10];
  if (i == 0) rowptr[0] = 0;
}

// nrm4[i] = {inv_in, sq_out, norm_in, norm_out}
__global__ void norms_kernel(const int* __restrict__ out_cnt, const int* __restrict__ in_cnt,
                             const int* __restrict__ rowptr,
                             float4* __restrict__ nrm4, int* __restrict__ cursor, int n) {
  int i = blockIdx.x * blockDim.x + threadIdx.x;
  if (i < n) {
    float od = (float)max(out_cnt[i], 1);
    float id = (float)max(in_cnt[i], 1);
    float4 v;
    v.x = 1.0f / id;      // inv_in
    v.y = sqrtf(od);      // sq_out  (undoes norm_out for the self-loop term)
    v.z = rsqrtf(id);     // norm_in
    v.w = rsqrtf(od);     // norm_out
    nrm4[i] = v;
    cursor[i] = rowptr[i];
  }
}

// xs = x * norm_out (row-wise)
__global__ void prescale_kernel(const float4* __restrict__ x4, const float4* __restrict__ nrm4,
                                float4* __restrict__ xs4, int n16) {
  int i = blockIdx.x * blockDim.x + threadIdx.x;
  if (i < n16) {
    float no = nrm4[i >> 4].w;
    float4 v = x4[i];
    v.x *= no; v.y *= no; v.z *= no; v.w *= no;
    xs4[i] = v;
  }
}

__global__ void fill_csr(const int* __restrict__ src, const int* __restrict__ dst,
                         const int* __restrict__ et, int* __restrict__ cursor,
                         int* __restrict__ ce, int E) {
  int i = blockIdx.x * blockDim.x + threadIdx.x;
  int stride = gridDim.x * blockDim.x;
  for (int e = i; e < E; e += stride) {
    int d = dst[e];
    int pos = atomicAdd(&cursor[d], 1);
    ce[pos] = src[e] | (et[e] << 20);   // src < 2^17, etype < 2^6
  }
}

// Fused RGCN layer. Wave = 1 node.
// Edge phase: groups g=0..3 (16 lanes), lane owns cols 4l..4l+3 (float4),
//   edges strided by group, unroll x2 (two gather chains in flight/group).
// Dense phase: W in LDS, lane = col = lane, k-loop row-broadcast ds_read_b32
//   (banks 2-way aliased only = free), xrow[k] wave-uniform global loads.
// Combine: butterfly-reduce edge float4 across groups, transpose to scalar
//   col=lane via 4 shfl + selects, fold norms, relu, coalesced b32 store.
template <bool FINAL>
__launch_bounds__(256, 8)
__global__ void layer_kernel(const float* __restrict__ xs, const float* __restrict__ W,
                             const float* __restrict__ relw,
                             const int* __restrict__ rowptr, const int* __restrict__ ce,
                             const float4* __restrict__ nrm4,
                             float* __restrict__ xout, int n) {
  __shared__ float Wl[4096];   // 16 KB, row-major [k][c]
  {
    const float4* __restrict__ Wg = (const float4*)W;
    float4* Wl4 = (float4*)Wl;
    for (int i = threadIdx.x; i < 1024; i += 256) Wl4[i] = Wg[i];
  }
  __syncthreads();

  const int node = blockIdx.x * 4 + (threadIdx.x >> 6);
  if (node >= n) return;
  const int lane = threadIdx.x & 63;
  const int g = lane >> 4;
  const int l = lane & 15;

  const int rb = rowptr[node];
  const int re = rowptr[node + 1];
  const float4 nr = nrm4[node];  // {inv_in, sq_out, norm_in, norm_out}

  const float4* __restrict__ xs4 = (const float4*)xs;
  const float4* __restrict__ rw4 = (const float4*)relw;

  // ---- edge aggregation: group g takes edges rb+g, rb+g+4, ...; unroll x2 ----
  float4 acc0 = {0.f, 0.f, 0.f, 0.f};
  float4 acc1 = {0.f, 0.f, 0.f, 0.f};
  int e = rb + g;
  for (; e + 4 < re; e += 8) {
    const int p0 = ce[e];
    const int p1 = ce[e + 4];
    const int s0 = p0 & 0xFFFFF, t0 = p0 >> 20;
    const int s1 = p1 & 0xFFFFF, t1 = p1 >> 20;
    const float4 xv0 = xs4[(size_t)s0 * 16 + l];
    const float4 xv1 = xs4[(size_t)s1 * 16 + l];
    const float4 rv0 = rw4[t0 * 16 + l];
    const float4 rv1 = rw4[t1 * 16 + l];
    acc0.x = fmaf(xv0.x, rv0.x, acc0.x);
    acc0.y = fmaf(xv0.y, rv0.y, acc0.y);
    acc0.z = fmaf(xv0.z, rv0.z, acc0.z);
    acc0.w = fmaf(xv0.w, rv0.w, acc0.w);
    acc1.x = fmaf(xv1.x, rv1.x, acc1.x);
    acc1.y = fmaf(xv1.y, rv1.y, acc1.y);
    acc1.z = fmaf(xv1.z, rv1.z, acc1.z);
    acc1.w = fmaf(xv1.w, rv1.w, acc1.w);
  }
  if (e < re) {
    const int p = ce[e];
    const int s = p & 0xFFFFF, t = p >> 20;
    const float4 xv = xs4[(size_t)s * 16 + l];
    const float4 rv = rw4[t * 16 + l];
    acc0.x = fmaf(xv.x, rv.x, acc0.x);
    acc0.y = fmaf(xv.y, rv.y, acc0.y);
    acc0.z = fmaf(xv.z, rv.z, acc0.z);
    acc0.w = fmaf(xv.w, rv.w, acc0.w);
  }
  float4 pre;
  pre.x = acc0.x + acc1.x;
  pre.y = acc0.y + acc1.y;
  pre.z = acc0.z + acc1.z;
  pre.w = acc0.w + acc1.w;

  // butterfly-reduce across the 4 groups (result lands in ALL lanes)
  pre.x += __shfl_xor(pre.x, 16); pre.x += __shfl_xor(pre.x, 32);
  pre.y += __shfl_xor(pre.y, 16); pre.y += __shfl_xor(pre.y, 32);
  pre.z += __shfl_xor(pre.z, 16); pre.z += __shfl_xor(pre.z, 32);
  pre.w += __shfl_xor(pre.w, 16); pre.w += __shfl_xor(pre.w, 32);

  // transpose float4-per-16lane -> scalar col=lane
  const int srcl = lane >> 2;
  const float t0 = __shfl(pre.x, srcl);
  const float t1 = __shfl(pre.y, srcl);
  const float t2 = __shfl(pre.z, srcl);
  const float t3 = __shfl(pre.w, srcl);
  const float ea = (lane & 2) ? ((lane & 1) ? t3 : t2)
                              : ((lane & 1) ? t1 : t0);

  // ---- dense self-loop: lane = col, k-loop over LDS rows (broadcast) ----
  float d0 = 0.f, d1 = 0.f, d2 = 0.f, d3 = 0.f;
  const float* __restrict__ xrow = xs + (size_t)node * 64;
#pragma unroll
  for (int k = 0; k < 64; k += 4) {
    d0 = fmaf(xrow[k],     Wl[(k)     * 64 + lane], d0);
    d1 = fmaf(xrow[k + 1], Wl[(k + 1) * 64 + lane], d1);
    d2 = fmaf(xrow[k + 2], Wl[(k + 2) * 64 + lane], d2);
    d3 = fmaf(xrow[k + 3], Wl[(k + 3) * 64 + lane], d3);
  }
  const float dense = (d0 + d1) + (d2 + d3);

  // relu(a)*c == relu(a*c) for c>0: fold norm_in (and norm_out if !FINAL)
  const float scale = FINAL ? nr.z : nr.z * nr.w;
  const float r = fmaf(ea, nr.x, dense * nr.y) * scale;
  xout[(size_t)node * 64 + lane] = fmaxf(r, 0.f);
}

extern "C" void kernel_launch(void* const* d_in, const int* in_sizes, int n_in,
                              void* d_out, int out_size, void* d_ws, size_t ws_size,
                              hipStream_t stream) {
  const float* x     = (const float*)d_in[0];
  const float* relw  = (const float*)d_in[1];
  const float* w1    = (const float*)d_in[2];
  const float* w2    = (const float*)d_in[3];
  const int*   src   = (const int*)d_in[4];
  const int*   dst   = (const int*)d_in[5];
  const int*   etype = (const int*)d_in[6];

  const int N = in_sizes[0] / 64;
  const int E = in_sizes[4];

  char* w = (char*)d_ws;
  size_t off = 0;
  auto alloc = [&](size_t bytes) -> void* {
    void* p = w + off;
    off = (off + bytes + 255) & ~(size_t)255;
    return p;
  };
  int*    out_cnt = (int*)alloc((size_t)N * 4);     // zeroed (contiguous with in_cnt)
  int*    in_cnt  = (int*)alloc((size_t)N * 4);
  int*    rowptr  = (int*)alloc((size_t)(N + 1) * 4);
  int*    cursor  = (int*)alloc((size_t)N * 4);
  float4* nrm4    = (float4*)alloc((size_t)N * 16);
  int*    bsums   = (int*)alloc(256 * 4);
  int*    boff    = (int*)alloc(256 * 4);
  int*    ce      = (int*)alloc((size_t)E * 4);     // packed src|etype<<20
  float*  xs      = (float*)alloc((size_t)N * 64 * 4);  // prescaled layer-1 input
  float*  h1s     = (float*)alloc((size_t)N * 64 * 4);  // prescaled layer-1 output

  // zero the two degree arrays (contiguous in ws)
  hipMemsetAsync(out_cnt, 0, ((char*)rowptr - (char*)out_cnt), stream);

  const int nb = (N + SCAN_BLK - 1) / SCAN_BLK;

  deg_kernel<<<4096, 256, 0, stream>>>(src, dst, out_cnt, in_cnt, E);
  scan_a<<<nb, SCAN_BLK, 0, stream>>>(in_cnt, rowptr + 1, bsums, N);
  scan_b<<<1, 256, 0, stream>>>(bsums, boff, nb);
  scan_c<<<(N + 255) / 256, 256, 0, stream>>>(rowptr, boff, N);
  norms_kernel<<<(N + 255) / 256, 256, 0, stream>>>(out_cnt, in_cnt, rowptr, nrm4, cursor, N);
  prescale_kernel<<<(N * 16 + 255) / 256, 256, 0, stream>>>((const float4*)x, nrm4,
                                                            (float4*)xs, N * 16);
  fill_csr<<<4096, 256, 0, stream>>>(src, dst, etype, cursor, ce, E);

  const int lblocks = (N + 3) / 4;
  layer_kernel<false><<<lblocks, 256, 0, stream>>>(xs, w1, relw, rowptr, ce, nrm4, h1s, N);
  layer_kernel<true><<<lblocks, 256, 0, stream>>>(h1s, w2, relw, rowptr, ce, nrm4,
                                                  (float*)d_out, N);
}

// Round 8
// 439.726 us; speedup vs baseline: 1.6876x; 1.0584x over previous
//
#include <hip/hip_runtime.h>

// RGCN 2-layer fused, MI355X. dst-CSR built once per call.
// R8: self-loop matvec hoisted OUT of the hot layer kernel into a streaming
// VGPR-resident GEMM (selfloop_kernel); layer kernel = pure edge gather +
// y-row add. scan_c + norms fused. No LDS anywhere, no float atomics.

#define SCAN_BLK 1024

__global__ void deg_kernel(const int* __restrict__ src, const int* __restrict__ dst,
                           int* __restrict__ out_cnt, int* __restrict__ in_cnt, int E) {
  int i = blockIdx.x * blockDim.x + threadIdx.x;
  int stride = gridDim.x * blockDim.x;
  for (int e = i; e < E; e += stride) {
    atomicAdd(&out_cnt[src[e]], 1);
    atomicAdd(&in_cnt[dst[e]], 1);
  }
}

// Per-block inclusive scan of in_cnt -> rowptr[i+1] (block-local); block sums out.
__global__ void scan_a(const int* __restrict__ in, int* __restrict__ out1,
                       int* __restrict__ bsums, int n) {
  __shared__ int tmp[SCAN_BLK];
  int i = blockIdx.x * SCAN_BLK + threadIdx.x;
  tmp[threadIdx.x] = (i < n) ? in[i] : 0;
  __syncthreads();
  for (int off = 1; off < SCAN_BLK; off <<= 1) {
    int t = (threadIdx.x >= off) ? tmp[threadIdx.x - off] : 0;
    __syncthreads();
    tmp[threadIdx.x] += t;
    __syncthreads();
  }
  if (i < n) out1[i] = tmp[threadIdx.x];
  if (threadIdx.x == SCAN_BLK - 1) bsums[blockIdx.x] = tmp[SCAN_BLK - 1];
}

// Parallel exclusive scan of block sums (nb <= 256), single block.
__global__ void scan_b(const int* __restrict__ bsums, int* __restrict__ boff, int nb) {
  __shared__ int t[256];
  int v = (threadIdx.x < nb) ? bsums[threadIdx.x] : 0;
  t[threadIdx.x] = v;
  __syncthreads();
  for (int off = 1; off < 256; off <<= 1) {
    int u = (threadIdx.x >= off) ? t[threadIdx.x - off] : 0;
    __syncthreads();
    t[threadIdx.x] += u;
    __syncthreads();
  }
  if (threadIdx.x < nb) boff[threadIdx.x] = t[threadIdx.x] - v;  // exclusive
}

// Fused: finalize rowptr into rowfin (race-free separate array), init cursor,
// compute norms. nrm4[i] = {inv_in, sq_out, norm_in, norm_out}.
__global__ void scan_c2(const int* __restrict__ rowptr, const int* __restrict__ boff,
                        const int* __restrict__ out_cnt, const int* __restrict__ in_cnt,
                        int* __restrict__ rowfin, int* __restrict__ cursor,
                        float4* __restrict__ nrm4, int n) {
  int i = blockIdx.x * blockDim.x + threadIdx.x;
  if (i < n) {
    rowfin[i + 1] = rowptr[i + 1] + boff[i >> 10];
    int rp0 = (i == 0) ? 0 : rowptr[i] + boff[(i - 1) >> 10];
    if (i == 0) rowfin[0] = 0;
    cursor[i] = rp0;
    float od = (float)max(out_cnt[i], 1);
    float id = (float)max(in_cnt[i], 1);
    float4 v;
    v.x = 1.0f / id;      // inv_in
    v.y = sqrtf(od);      // sq_out
    v.z = rsqrtf(id);     // norm_in
    v.w = rsqrtf(od);     // norm_out
    nrm4[i] = v;
  }
}

// xs = x * norm_out (row-wise)
__global__ void prescale_kernel(const float4* __restrict__ x4, const float4* __restrict__ nrm4,
                                float4* __restrict__ xs4, int n16) {
  int i = blockIdx.x * blockDim.x + threadIdx.x;
  if (i < n16) {
    float no = nrm4[i >> 4].w;
    float4 v = x4[i];
    v.x *= no; v.y *= no; v.z *= no; v.w *= no;
    xs4[i] = v;
  }
}

__global__ void fill_csr(const int* __restrict__ src, const int* __restrict__ dst,
                         const int* __restrict__ et, int* __restrict__ cursor,
                         int* __restrict__ ce, int E) {
  int i = blockIdx.x * blockDim.x + threadIdx.x;
  int stride = gridDim.x * blockDim.x;
  for (int e = i; e < E; e += stride) {
    int d = dst[e];
    int pos = atomicAdd(&cursor[d], 1);
    ce[pos] = src[e] | (et[e] << 20);   // src < 2^17, etype < 2^6
  }
}

// Self-loop GEMM: y[node][lane] = (xs[node,:] . W[:,lane]) * sq_out[node].
// Wave = node (grid-stride). W column in 64 VGPRs (compile-time indexed).
// xrow via wave-uniform loads (readfirstlane -> scalar/SMEM path).
__launch_bounds__(256, 4)
__global__ void selfloop_kernel(const float* __restrict__ xs, const float* __restrict__ W,
                                const float4* __restrict__ nrm4,
                                float* __restrict__ y, int n) {
  const int lane = threadIdx.x & 63;
  float wc[64];
#pragma unroll
  for (int k = 0; k < 64; ++k) wc[k] = W[k * 64 + lane];   // coalesced
  const int wid = (blockIdx.x * blockDim.x + threadIdx.x) >> 6;
  const int nw = (gridDim.x * blockDim.x) >> 6;
  for (int node0 = wid; node0 < n; node0 += nw) {
    const int node = __builtin_amdgcn_readfirstlane(node0);
    const float* __restrict__ xrow = xs + (size_t)node * 64;
    float d0 = 0.f, d1 = 0.f, d2 = 0.f, d3 = 0.f;
#pragma unroll
    for (int k = 0; k < 64; k += 4) {
      d0 = fmaf(xrow[k],     wc[k],     d0);
      d1 = fmaf(xrow[k + 1], wc[k + 1], d1);
      d2 = fmaf(xrow[k + 2], wc[k + 2], d2);
      d3 = fmaf(xrow[k + 3], wc[k + 3], d3);
    }
    y[(size_t)node * 64 + lane] = ((d0 + d1) + (d2 + d3)) * nrm4[node].y;
  }
}

// Edge-only RGCN layer. Wave = 1 node. Groups g=0..3 (16 lanes), lane owns
// cols 4l..4l+3 (float4), edges strided by group, unroll x2. Butterfly-reduce
// + transpose to col=lane, add precomputed self-loop row y, norms, relu.
template <bool FINAL>
__launch_bounds__(256, 8)
__global__ void layer_kernel(const float* __restrict__ xs, const float* __restrict__ y,
                             const float* __restrict__ relw,
                             const int* __restrict__ rowptr, const int* __restrict__ ce,
                             const float4* __restrict__ nrm4,
                             float* __restrict__ xout, int n) {
  const int node = blockIdx.x * 4 + (threadIdx.x >> 6);
  if (node >= n) return;
  const int lane = threadIdx.x & 63;
  const int g = lane >> 4;
  const int l = lane & 15;

  const int rb = rowptr[node];
  const int re = rowptr[node + 1];
  const float4 nr = nrm4[node];  // {inv_in, sq_out, norm_in, norm_out}

  const float4* __restrict__ xs4 = (const float4*)xs;
  const float4* __restrict__ rw4 = (const float4*)relw;

  // ---- edge aggregation: group g takes edges rb+g, rb+g+4, ...; unroll x2 ----
  float4 acc0 = {0.f, 0.f, 0.f, 0.f};
  float4 acc1 = {0.f, 0.f, 0.f, 0.f};
  int e = rb + g;
  for (; e + 4 < re; e += 8) {
    const int p0 = ce[e];
    const int p1 = ce[e + 4];
    const int s0 = p0 & 0xFFFFF, t0 = p0 >> 20;
    const int s1 = p1 & 0xFFFFF, t1 = p1 >> 20;
    const float4 xv0 = xs4[(size_t)s0 * 16 + l];
    const float4 xv1 = xs4[(size_t)s1 * 16 + l];
    const float4 rv0 = rw4[t0 * 16 + l];
    const float4 rv1 = rw4[t1 * 16 + l];
    acc0.x = fmaf(xv0.x, rv0.x, acc0.x);
    acc0.y = fmaf(xv0.y, rv0.y, acc0.y);
    acc0.z = fmaf(xv0.z, rv0.z, acc0.z);
    acc0.w = fmaf(xv0.w, rv0.w, acc0.w);
    acc1.x = fmaf(xv1.x, rv1.x, acc1.x);
    acc1.y = fmaf(xv1.y, rv1.y, acc1.y);
    acc1.z = fmaf(xv1.z, rv1.z, acc1.z);
    acc1.w = fmaf(xv1.w, rv1.w, acc1.w);
  }
  if (e < re) {
    const int p = ce[e];
    const int s = p & 0xFFFFF, t = p >> 20;
    const float4 xv = xs4[(size_t)s * 16 + l];
    const float4 rv = rw4[t * 16 + l];
    acc0.x = fmaf(xv.x, rv.x, acc0.x);
    acc0.y = fmaf(xv.y, rv.y, acc0.y);
    acc0.z = fmaf(xv.z, rv.z, acc0.z);
    acc0.w = fmaf(xv.w, rv.w, acc0.w);
  }
  float4 pre;
  pre.x = acc0.x + acc1.x;
  pre.y = acc0.y + acc1.y;
  pre.z = acc0.z + acc1.z;
  pre.w = acc0.w + acc1.w;

  // butterfly-reduce across the 4 groups (result lands in ALL lanes)
  pre.x += __shfl_xor(pre.x, 16); pre.x += __shfl_xor(pre.x, 32);
  pre.y += __shfl_xor(pre.y, 16); pre.y += __shfl_xor(pre.y, 32);
  pre.z += __shfl_xor(pre.z, 16); pre.z += __shfl_xor(pre.z, 32);
  pre.w += __shfl_xor(pre.w, 16); pre.w += __shfl_xor(pre.w, 32);

  // transpose float4-per-16lane -> scalar col=lane
  const int srcl = lane >> 2;
  const float t0 = __shfl(pre.x, srcl);
  const float t1 = __shfl(pre.y, srcl);
  const float t2 = __shfl(pre.z, srcl);
  const float t3 = __shfl(pre.w, srcl);
  const float ea = (lane & 2) ? ((lane & 1) ? t3 : t2)
                              : ((lane & 1) ? t1 : t0);

  // self-loop row (precomputed, already * sq_out): coalesced b32
  const float yv = y[(size_t)node * 64 + lane];

  // relu(a)*c == relu(a*c) for c>0: fold norm_in (and norm_out if !FINAL)
  const float scale = FINAL ? nr.z : nr.z * nr.w;
  const float r = fmaf(ea, nr.x, yv) * scale;
  xout[(size_t)node * 64 + lane] = fmaxf(r, 0.f);
}

extern "C" void kernel_launch(void* const* d_in, const int* in_sizes, int n_in,
                              void* d_out, int out_size, void* d_ws, size_t ws_size,
                              hipStream_t stream) {
  const float* x     = (const float*)d_in[0];
  const float* relw  = (const float*)d_in[1];
  const float* w1    = (const float*)d_in[2];
  const float* w2    = (const float*)d_in[3];
  const int*   src   = (const int*)d_in[4];
  const int*   dst   = (const int*)d_in[5];
  const int*   etype = (const int*)d_in[6];

  const int N = in_sizes[0] / 64;
  const int E = in_sizes[4];

  char* w = (char*)d_ws;
  size_t off = 0;
  auto alloc = [&](size_t bytes) -> void* {
    void* p = w + off;
    off = (off + bytes + 255) & ~(size_t)255;
    return p;
  };
  int*    out_cnt = (int*)alloc((size_t)N * 4);     // zeroed (contiguous with in_cnt)
  int*    in_cnt  = (int*)alloc((size_t)N * 4);
  int*    rowptr  = (int*)alloc((size_t)(N + 1) * 4);   // partial (scan_a output)
  int*    rowfin  = (int*)alloc((size_t)(N + 1) * 4);   // final CSR rowptr
  int*    cursor  = (int*)alloc((size_t)N * 4);
  float4* nrm4    = (float4*)alloc((size_t)N * 16);
  int*    bsums   = (int*)alloc(256 * 4);
  int*    boff    = (int*)alloc(256 * 4);
  int*    ce      = (int*)alloc((size_t)E * 4);     // packed src|etype<<20
  float*  xs      = (float*)alloc((size_t)N * 64 * 4);  // prescaled layer-1 input
  float*  h1s     = (float*)alloc((size_t)N * 64 * 4);  // prescaled layer-1 output
  float*  y       = (float*)alloc((size_t)N * 64 * 4);  // self-loop rows (per layer)

  // zero the two degree arrays (contiguous in ws)
  hipMemsetAsync(out_cnt, 0, ((char*)rowptr - (char*)out_cnt), stream);

  const int nb = (N + SCAN_BLK - 1) / SCAN_BLK;

  deg_kernel<<<4096, 256, 0, stream>>>(src, dst, out_cnt, in_cnt, E);
  scan_a<<<nb, SCAN_BLK, 0, stream>>>(in_cnt, rowptr + 1, bsums, N);
  scan_b<<<1, 256, 0, stream>>>(bsums, boff, nb);
  scan_c2<<<(N + 255) / 256, 256, 0, stream>>>(rowptr, boff, out_cnt, in_cnt,
                                               rowfin, cursor, nrm4, N);
  prescale_kernel<<<(N * 16 + 255) / 256, 256, 0, stream>>>((const float4*)x, nrm4,
                                                            (float4*)xs, N * 16);
  fill_csr<<<4096, 256, 0, stream>>>(src, dst, etype, cursor, ce, E);

  const int lblocks = (N + 3) / 4;
  selfloop_kernel<<<4096, 256, 0, stream>>>(xs, w1, nrm4, y, N);
  layer_kernel<false><<<lblocks, 256, 0, stream>>>(xs, y, relw, rowfin, ce, nrm4, h1s, N);
  selfloop_kernel<<<4096, 256, 0, stream>>>(h1s, w2, nrm4, y, N);
  layer_kernel<true><<<lblocks, 256, 0, stream>>>(h1s, y, relw, rowfin, ce, nrm4,
                                                  (float*)d_out, N);
}

// Round 9
// 384.405 us; speedup vs baseline: 1.9304x; 1.1439x over previous
//
#include <hip/hip_runtime.h>

// RGCN 2-layer fused, MI355X. dst-CSR built once per call.
// R9: atomic diet. Degrees+ranks in ONE pass (2.4M atomics, down from 3.6M);
// CSR fill is atomic-free via precomputed ranks (slot = rowptr[dst]+rank).
// Layers: edge-gather-only kernel (self-loop matvec hoisted to streaming
// VGPR GEMM). No float atomics anywhere.

#define SCAN_BLK 1024

// rank[e] = arrival index of edge e within its dst bucket; also counts degrees.
__global__ void deg_rank_kernel(const int* __restrict__ src, const int* __restrict__ dst,
                                int* __restrict__ out_cnt, int* __restrict__ in_cnt,
                                int* __restrict__ rank, int E) {
  int i = blockIdx.x * blockDim.x + threadIdx.x;
  int stride = gridDim.x * blockDim.x;
  for (int e = i; e < E; e += stride) {
    rank[e] = atomicAdd(&in_cnt[dst[e]], 1);
    atomicAdd(&out_cnt[src[e]], 1);
  }
}

// Per-block inclusive scan of in_cnt -> rowptr[i+1] (block-local); block sums out.
__global__ void scan_a(const int* __restrict__ in, int* __restrict__ out1,
                       int* __restrict__ bsums, int n) {
  __shared__ int tmp[SCAN_BLK];
  int i = blockIdx.x * SCAN_BLK + threadIdx.x;
  tmp[threadIdx.x] = (i < n) ? in[i] : 0;
  __syncthreads();
  for (int off = 1; off < SCAN_BLK; off <<= 1) {
    int t = (threadIdx.x >= off) ? tmp[threadIdx.x - off] : 0;
    __syncthreads();
    tmp[threadIdx.x] += t;
    __syncthreads();
  }
  if (i < n) out1[i] = tmp[threadIdx.x];
  if (threadIdx.x == SCAN_BLK - 1) bsums[blockIdx.x] = tmp[SCAN_BLK - 1];
}

// Parallel exclusive scan of block sums (nb <= 256), single block.
__global__ void scan_b(const int* __restrict__ bsums, int* __restrict__ boff, int nb) {
  __shared__ int t[256];
  int v = (threadIdx.x < nb) ? bsums[threadIdx.x] : 0;
  t[threadIdx.x] = v;
  __syncthreads();
  for (int off = 1; off < 256; off <<= 1) {
    int u = (threadIdx.x >= off) ? t[threadIdx.x - off] : 0;
    __syncthreads();
    t[threadIdx.x] += u;
    __syncthreads();
  }
  if (threadIdx.x < nb) boff[threadIdx.x] = t[threadIdx.x] - v;  // exclusive
}

// Fused: finalize rowptr into rowfin (race-free separate array) + norms.
// nrm4[i] = {inv_in, sq_out, norm_in, norm_out}.
__global__ void scan_c2(const int* __restrict__ rowptr, const int* __restrict__ boff,
                        const int* __restrict__ out_cnt, const int* __restrict__ in_cnt,
                        int* __restrict__ rowfin, float4* __restrict__ nrm4, int n) {
  int i = blockIdx.x * blockDim.x + threadIdx.x;
  if (i < n) {
    rowfin[i + 1] = rowptr[i + 1] + boff[i >> 10];
    if (i == 0) rowfin[0] = 0;
    float od = (float)max(out_cnt[i], 1);
    float id = (float)max(in_cnt[i], 1);
    float4 v;
    v.x = 1.0f / id;      // inv_in
    v.y = sqrtf(od);      // sq_out
    v.z = rsqrtf(id);     // norm_in
    v.w = rsqrtf(od);     // norm_out
    nrm4[i] = v;
  }
}

// xs = x * norm_out (row-wise)
__global__ void prescale_kernel(const float4* __restrict__ x4, const float4* __restrict__ nrm4,
                                float4* __restrict__ xs4, int n16) {
  int i = blockIdx.x * blockDim.x + threadIdx.x;
  if (i < n16) {
    float no = nrm4[i >> 4].w;
    float4 v = x4[i];
    v.x *= no; v.y *= no; v.z *= no; v.w *= no;
    xs4[i] = v;
  }
}

// Atomic-free CSR fill: each edge's slot is rowfin[dst]+rank (unique by
// construction). rowfin gathers are L2-resident (400 KB array).
__global__ void scatter_csr(const int* __restrict__ src, const int* __restrict__ dst,
                            const int* __restrict__ et, const int* __restrict__ rank,
                            const int* __restrict__ rowfin, int* __restrict__ ce, int E) {
  int i = blockIdx.x * blockDim.x + threadIdx.x;
  int stride = gridDim.x * blockDim.x;
  for (int e = i; e < E; e += stride) {
    ce[rowfin[dst[e]] + rank[e]] = src[e] | (et[e] << 20);  // src<2^17, et<2^6
  }
}

// Self-loop GEMM: y[node][lane] = (xs[node,:] . W[:,lane]) * sq_out[node].
// Wave = node (grid-stride). W column in 64 VGPRs (compile-time indexed).
__launch_bounds__(256, 4)
__global__ void selfloop_kernel(const float* __restrict__ xs, const float* __restrict__ W,
                                const float4* __restrict__ nrm4,
                                float* __restrict__ y, int n) {
  const int lane = threadIdx.x & 63;
  float wc[64];
#pragma unroll
  for (int k = 0; k < 64; ++k) wc[k] = W[k * 64 + lane];   // coalesced
  const int wid = (blockIdx.x * blockDim.x + threadIdx.x) >> 6;
  const int nw = (gridDim.x * blockDim.x) >> 6;
  for (int node0 = wid; node0 < n; node0 += nw) {
    const int node = __builtin_amdgcn_readfirstlane(node0);
    const float* __restrict__ xrow = xs + (size_t)node * 64;
    float d0 = 0.f, d1 = 0.f, d2 = 0.f, d3 = 0.f;
#pragma unroll
    for (int k = 0; k < 64; k += 4) {
      d0 = fmaf(xrow[k],     wc[k],     d0);
      d1 = fmaf(xrow[k + 1], wc[k + 1], d1);
      d2 = fmaf(xrow[k + 2], wc[k + 2], d2);
      d3 = fmaf(xrow[k + 3], wc[k + 3], d3);
    }
    y[(size_t)node * 64 + lane] = ((d0 + d1) + (d2 + d3)) * nrm4[node].y;
  }
}

// Edge-only RGCN layer. Wave = 1 node. Groups g=0..3 (16 lanes), lane owns
// cols 4l..4l+3 (float4), edges strided by group, unroll x2. Butterfly-reduce
// + transpose to col=lane, add precomputed self-loop row y, norms, relu.
template <bool FINAL>
__launch_bounds__(256, 8)
__global__ void layer_kernel(const float* __restrict__ xs, const float* __restrict__ y,
                             const float* __restrict__ relw,
                             const int* __restrict__ rowptr, const int* __restrict__ ce,
                             const float4* __restrict__ nrm4,
                             float* __restrict__ xout, int n) {
  const int node = blockIdx.x * 4 + (threadIdx.x >> 6);
  if (node >= n) return;
  const int lane = threadIdx.x & 63;
  const int g = lane >> 4;
  const int l = lane & 15;

  const int rb = rowptr[node];
  const int re = rowptr[node + 1];
  const float4 nr = nrm4[node];  // {inv_in, sq_out, norm_in, norm_out}

  const float4* __restrict__ xs4 = (const float4*)xs;
  const float4* __restrict__ rw4 = (const float4*)relw;

  // ---- edge aggregation: group g takes edges rb+g, rb+g+4, ...; unroll x2 ----
  float4 acc0 = {0.f, 0.f, 0.f, 0.f};
  float4 acc1 = {0.f, 0.f, 0.f, 0.f};
  int e = rb + g;
  for (; e + 4 < re; e += 8) {
    const int p0 = ce[e];
    const int p1 = ce[e + 4];
    const int s0 = p0 & 0xFFFFF, t0 = p0 >> 20;
    const int s1 = p1 & 0xFFFFF, t1 = p1 >> 20;
    const float4 xv0 = xs4[(size_t)s0 * 16 + l];
    const float4 xv1 = xs4[(size_t)s1 * 16 + l];
    const float4 rv0 = rw4[t0 * 16 + l];
    const float4 rv1 = rw4[t1 * 16 + l];
    acc0.x = fmaf(xv0.x, rv0.x, acc0.x);
    acc0.y = fmaf(xv0.y, rv0.y, acc0.y);
    acc0.z = fmaf(xv0.z, rv0.z, acc0.z);
    acc0.w = fmaf(xv0.w, rv0.w, acc0.w);
    acc1.x = fmaf(xv1.x, rv1.x, acc1.x);
    acc1.y = fmaf(xv1.y, rv1.y, acc1.y);
    acc1.z = fmaf(xv1.z, rv1.z, acc1.z);
    acc1.w = fmaf(xv1.w, rv1.w, acc1.w);
  }
  if (e < re) {
    const int p = ce[e];
    const int s = p & 0xFFFFF, t = p >> 20;
    const float4 xv = xs4[(size_t)s * 16 + l];
    const float4 rv = rw4[t * 16 + l];
    acc0.x = fmaf(xv.x, rv.x, acc0.x);
    acc0.y = fmaf(xv.y, rv.y, acc0.y);
    acc0.z = fmaf(xv.z, rv.z, acc0.z);
    acc0.w = fmaf(xv.w, rv.w, acc0.w);
  }
  float4 pre;
  pre.x = acc0.x + acc1.x;
  pre.y = acc0.y + acc1.y;
  pre.z = acc0.z + acc1.z;
  pre.w = acc0.w + acc1.w;

  // butterfly-reduce across the 4 groups (result lands in ALL lanes)
  pre.x += __shfl_xor(pre.x, 16); pre.x += __shfl_xor(pre.x, 32);
  pre.y += __shfl_xor(pre.y, 16); pre.y += __shfl_xor(pre.y, 32);
  pre.z += __shfl_xor(pre.z, 16); pre.z += __shfl_xor(pre.z, 32);
  pre.w += __shfl_xor(pre.w, 16); pre.w += __shfl_xor(pre.w, 32);

  // transpose float4-per-16lane -> scalar col=lane
  const int srcl = lane >> 2;
  const float t0 = __shfl(pre.x, srcl);
  const float t1 = __shfl(pre.y, srcl);
  const float t2 = __shfl(pre.z, srcl);
  const float t3 = __shfl(pre.w, srcl);
  const float ea = (lane & 2) ? ((lane & 1) ? t3 : t2)
                              : ((lane & 1) ? t1 : t0);

  // self-loop row (precomputed, already * sq_out): coalesced b32
  const float yv = y[(size_t)node * 64 + lane];

  // relu(a)*c == relu(a*c) for c>0: fold norm_in (and norm_out if !FINAL)
  const float scale = FINAL ? nr.z : nr.z * nr.w;
  const float r = fmaf(ea, nr.x, yv) * scale;
  xout[(size_t)node * 64 + lane] = fmaxf(r, 0.f);
}

extern "C" void kernel_launch(void* const* d_in, const int* in_sizes, int n_in,
                              void* d_out, int out_size, void* d_ws, size_t ws_size,
                              hipStream_t stream) {
  const float* x     = (const float*)d_in[0];
  const float* relw  = (const float*)d_in[1];
  const float* w1    = (const float*)d_in[2];
  const float* w2    = (const float*)d_in[3];
  const int*   src   = (const int*)d_in[4];
  const int*   dst   = (const int*)d_in[5];
  const int*   etype = (const int*)d_in[6];

  const int N = in_sizes[0] / 64;
  const int E = in_sizes[4];

  char* w = (char*)d_ws;
  size_t off = 0;
  auto alloc = [&](size_t bytes) -> void* {
    void* p = w + off;
    off = (off + bytes + 255) & ~(size_t)255;
    return p;
  };
  int*    out_cnt = (int*)alloc((size_t)N * 4);     // zeroed (contiguous with in_cnt)
  int*    in_cnt  = (int*)alloc((size_t)N * 4);
  int*    rowptr  = (int*)alloc((size_t)(N + 1) * 4);   // partial (scan_a output)
  int*    rowfin  = (int*)alloc((size_t)(N + 1) * 4);   // final CSR rowptr
  float4* nrm4    = (float4*)alloc((size_t)N * 16);
  int*    bsums   = (int*)alloc(256 * 4);
  int*    boff    = (int*)alloc(256 * 4);
  int*    rank    = (int*)alloc((size_t)E * 4);     // in-bucket arrival rank
  int*    ce      = (int*)alloc((size_t)E * 4);     // packed src|etype<<20
  float*  xs      = (float*)alloc((size_t)N * 64 * 4);  // prescaled layer-1 input
  float*  h1s     = (float*)alloc((size_t)N * 64 * 4);  // prescaled layer-1 output
  float*  y       = (float*)alloc((size_t)N * 64 * 4);  // self-loop rows (per layer)

  // zero the two degree arrays (contiguous in ws)
  hipMemsetAsync(out_cnt, 0, ((char*)rowptr - (char*)out_cnt), stream);

  const int nb = (N + SCAN_BLK - 1) / SCAN_BLK;

  deg_rank_kernel<<<4096, 256, 0, stream>>>(src, dst, out_cnt, in_cnt, rank, E);
  scan_a<<<nb, SCAN_BLK, 0, stream>>>(in_cnt, rowptr + 1, bsums, N);
  scan_b<<<1, 256, 0, stream>>>(bsums, boff, nb);
  scan_c2<<<(N + 255) / 256, 256, 0, stream>>>(rowptr, boff, out_cnt, in_cnt,
                                               rowfin, nrm4, N);
  prescale_kernel<<<(N * 16 + 255) / 256, 256, 0, stream>>>((const float4*)x, nrm4,
                                                            (float4*)xs, N * 16);
  scatter_csr<<<4096, 256, 0, stream>>>(src, dst, etype, rank, rowfin, ce, E);

  const int lblocks = (N + 3) / 4;
  selfloop_kernel<<<4096, 256, 0, stream>>>(xs, w1, nrm4, y, N);
  layer_kernel<false><<<lblocks, 256, 0, stream>>>(xs, y, relw, rowfin, ce, nrm4, h1s, N);
  selfloop_kernel<<<4096, 256, 0, stream>>>(h1s, w2, nrm4, y, N);
  layer_kernel<true><<<lblocks, 256, 0, stream>>>(h1s, y, relw, rowfin, ce, nrm4,
                                                  (float*)d_out, N);
}

// Round 12
// 372.313 us; speedup vs baseline: 1.9931x; 1.0325x over previous
//
#include <hip/hip_runtime.h>
#include <hip/hip_fp16.h>

// RGCN 2-layer fused, MI355X. dst-CSR built once per call.
// R10: fp16 feature storage (xs, h1, relw) -> halves the random gather line
// traffic that bounds the layer kernels. Accumulation stays fp32. Self-loop
// matvec is a separate streaming VGPR GEMM (y, fp32). CSR build: rank trick,
// no atomics in scatter. No float atomics anywhere.

#define SCAN_BLK 1024

// rank[e] = arrival index of edge e within its dst bucket; also counts degrees.
__global__ void deg_rank_kernel(const int* __restrict__ src, const int* __restrict__ dst,
                                int* __restrict__ out_cnt, int* __restrict__ in_cnt,
                                int* __restrict__ rank, int E) {
  int i = blockIdx.x * blockDim.x + threadIdx.x;
  int stride = gridDim.x * blockDim.x;
  for (int e = i; e < E; e += stride) {
    rank[e] = atomicAdd(&in_cnt[dst[e]], 1);
    atomicAdd(&out_cnt[src[e]], 1);
  }
}

// Per-block inclusive scan of in_cnt -> rowptr[i+1] (block-local); block sums out.
__global__ void scan_a(const int* __restrict__ in, int* __restrict__ out1,
                       int* __restrict__ bsums, int n) {
  __shared__ int tmp[SCAN_BLK];
  int i = blockIdx.x * SCAN_BLK + threadIdx.x;
  tmp[threadIdx.x] = (i < n) ? in[i] : 0;
  __syncthreads();
  for (int off = 1; off < SCAN_BLK; off <<= 1) {
    int t = (threadIdx.x >= off) ? tmp[threadIdx.x - off] : 0;
    __syncthreads();
    tmp[threadIdx.x] += t;
    __syncthreads();
  }
  if (i < n) out1[i] = tmp[threadIdx.x];
  if (threadIdx.x == SCAN_BLK - 1) bsums[blockIdx.x] = tmp[SCAN_BLK - 1];
}

// Parallel exclusive scan of block sums (nb <= 256), single block.
__global__ void scan_b(const int* __restrict__ bsums, int* __restrict__ boff, int nb) {
  __shared__ int t[256];
  int v = (threadIdx.x < nb) ? bsums[threadIdx.x] : 0;
  t[threadIdx.x] = v;
  __syncthreads();
  for (int off = 1; off < 256; off <<= 1) {
    int u = (threadIdx.x >= off) ? t[threadIdx.x - off] : 0;
    __syncthreads();
    t[threadIdx.x] += u;
    __syncthreads();
  }
  if (threadIdx.x < nb) boff[threadIdx.x] = t[threadIdx.x] - v;  // exclusive
}

// Fused: finalize rowptr into rowfin (race-free separate array) + norms.
// nrm4[i] = {inv_in, sq_out, norm_in, norm_out}.
__global__ void scan_c2(const int* __restrict__ rowptr, const int* __restrict__ boff,
                        const int* __restrict__ out_cnt, const int* __restrict__ in_cnt,
                        int* __restrict__ rowfin, float4* __restrict__ nrm4, int n) {
  int i = blockIdx.x * blockDim.x + threadIdx.x;
  if (i < n) {
    rowfin[i + 1] = rowptr[i + 1] + boff[i >> 10];
    if (i == 0) rowfin[0] = 0;
    float od = (float)max(out_cnt[i], 1);
    float id = (float)max(in_cnt[i], 1);
    float4 v;
    v.x = 1.0f / id;      // inv_in
    v.y = sqrtf(od);      // sq_out
    v.z = rsqrtf(id);     // norm_in
    v.w = rsqrtf(od);     // norm_out
    nrm4[i] = v;
  }
}

// load 4 packed halves -> float4
__device__ inline float4 ldh4(const uint2* __restrict__ p, size_t idx) {
  const uint2 v = p[idx];
  const __half2 a = *reinterpret_cast<const __half2*>(&v.x);
  const __half2 b = *reinterpret_cast<const __half2*>(&v.y);
  const float2 fa = __half22float2(a);
  const float2 fb = __half22float2(b);
  return make_float4(fa.x, fa.y, fb.x, fb.y);
}

// xs_h = half(x * norm_out), packed 4 halves per uint2; i indexes 4-col groups.
__global__ void prescale_h(const float4* __restrict__ x4, const float4* __restrict__ nrm4,
                           uint2* __restrict__ xsh, int n16) {
  int i = blockIdx.x * blockDim.x + threadIdx.x;
  if (i < n16) {
    float no = nrm4[i >> 4].w;
    float4 v = x4[i];
    __half2 h01 = __floats2half2_rn(v.x * no, v.y * no);
    __half2 h23 = __floats2half2_rn(v.z * no, v.w * no);
    uint2 o;
    o.x = *reinterpret_cast<unsigned int*>(&h01);
    o.y = *reinterpret_cast<unsigned int*>(&h23);
    xsh[i] = o;
  }
}

// relw fp32 -> fp16 packed (50*64 elements, 800 uint2)
__global__ void cvt_relw(const float4* __restrict__ rw4, uint2* __restrict__ rwh, int n4) {
  int i = blockIdx.x * blockDim.x + threadIdx.x;
  if (i < n4) {
    float4 v = rw4[i];
    __half2 h01 = __floats2half2_rn(v.x, v.y);
    __half2 h23 = __floats2half2_rn(v.z, v.w);
    uint2 o;
    o.x = *reinterpret_cast<unsigned int*>(&h01);
    o.y = *reinterpret_cast<unsigned int*>(&h23);
    rwh[i] = o;
  }
}

// Atomic-free CSR fill: each edge's slot is rowfin[dst]+rank (unique by
// construction). rowfin gathers are L2-resident (400 KB array).
__global__ void scatter_csr(const int* __restrict__ src, const int* __restrict__ dst,
                            const int* __restrict__ et, const int* __restrict__ rank,
                            const int* __restrict__ rowfin, int* __restrict__ ce, int E) {
  int i = blockIdx.x * blockDim.x + threadIdx.x;
  int stride = gridDim.x * blockDim.x;
  for (int e = i; e < E; e += stride) {
    ce[rowfin[dst[e]] + rank[e]] = src[e] | (et[e] << 20);  // src<2^17, et<2^6
  }
}

// Self-loop GEMM: y[node][lane] = (xs[node,:] . W[:,lane]) * sq_out[node].
// Wave = node (grid-stride). W column in 64 VGPRs; xs rows read fp16 uniform.
__launch_bounds__(256, 4)
__global__ void selfloop_kernel(const uint2* __restrict__ xsh, const float* __restrict__ W,
                                const float4* __restrict__ nrm4,
                                float* __restrict__ y, int n) {
  const int lane = threadIdx.x & 63;
  float wc[64];
#pragma unroll
  for (int k = 0; k < 64; ++k) wc[k] = W[k * 64 + lane];   // coalesced
  const int wid = (blockIdx.x * blockDim.x + threadIdx.x) >> 6;
  const int nw = (gridDim.x * blockDim.x) >> 6;
  for (int node0 = wid; node0 < n; node0 += nw) {
    const int node = __builtin_amdgcn_readfirstlane(node0);
    const uint2* __restrict__ xr = xsh + (size_t)node * 16;
    float d0 = 0.f, d1 = 0.f, d2 = 0.f, d3 = 0.f;
#pragma unroll
    for (int kk = 0; kk < 16; ++kk) {
      const float4 v = ldh4(xr, kk);
      const int k = kk << 2;
      d0 = fmaf(v.x, wc[k],     d0);
      d1 = fmaf(v.y, wc[k + 1], d1);
      d2 = fmaf(v.z, wc[k + 2], d2);
      d3 = fmaf(v.w, wc[k + 3], d3);
    }
    y[(size_t)node * 64 + lane] = ((d0 + d1) + (d2 + d3)) * nrm4[node].y;
  }
}

// Edge-only RGCN layer, fp16 gathers. Wave = 1 node. Groups g=0..3 (16 lanes),
// lane owns cols 4l..4l+3 (uint2 = 4 halves), edges strided by group, unroll
// x2. Butterfly-reduce + transpose to col=lane, add self-loop row y (fp32),
// norms, relu. Output: fp16 (hidden) or fp32 (final).
template <bool FINAL>
__launch_bounds__(256, 8)
__global__ void layer_kernel(const uint2* __restrict__ xsh, const float* __restrict__ y,
                             const uint2* __restrict__ rwh,
                             const int* __restrict__ rowptr, const int* __restrict__ ce,
                             const float4* __restrict__ nrm4,
                             void* __restrict__ xout, int n) {
  const int node = blockIdx.x * 4 + (threadIdx.x >> 6);
  if (node >= n) return;
  const int lane = threadIdx.x & 63;
  const int g = lane >> 4;
  const int l = lane & 15;

  const int rb = rowptr[node];
  const int re = rowptr[node + 1];
  const float4 nr = nrm4[node];  // {inv_in, sq_out, norm_in, norm_out}

  // ---- edge aggregation: group g takes edges rb+g, rb+g+4, ...; unroll x2 ----
  float4 acc0 = {0.f, 0.f, 0.f, 0.f};
  float4 acc1 = {0.f, 0.f, 0.f, 0.f};
  int e = rb + g;
  for (; e + 4 < re; e += 8) {
    const int p0 = ce[e];
    const int p1 = ce[e + 4];
    const int s0 = p0 & 0xFFFFF, t0 = p0 >> 20;
    const int s1 = p1 & 0xFFFFF, t1 = p1 >> 20;
    const float4 xv0 = ldh4(xsh, (size_t)s0 * 16 + l);
    const float4 xv1 = ldh4(xsh, (size_t)s1 * 16 + l);
    const float4 rv0 = ldh4(rwh, t0 * 16 + l);
    const float4 rv1 = ldh4(rwh, t1 * 16 + l);
    acc0.x = fmaf(xv0.x, rv0.x, acc0.x);
    acc0.y = fmaf(xv0.y, rv0.y, acc0.y);
    acc0.z = fmaf(xv0.z, rv0.z, acc0.z);
    acc0.w = fmaf(xv0.w, rv0.w, acc0.w);
    acc1.x = fmaf(xv1.x, rv1.x, acc1.x);
    acc1.y = fmaf(xv1.y, rv1.y, acc1.y);
    acc1.z = fmaf(xv1.z, rv1.z, acc1.z);
    acc1.w = fmaf(xv1.w, rv1.w, acc1.w);
  }
  if (e < re) {
    const int p = ce[e];
    const int s = p & 0xFFFFF, t = p >> 20;
    const float4 xv = ldh4(xsh, (size_t)s * 16 + l);
    const float4 rv = ldh4(rwh, t * 16 + l);
    acc0.x = fmaf(xv.x, rv.x, acc0.x);
    acc0.y = fmaf(xv.y, rv.y, acc0.y);
    acc0.z = fmaf(xv.z, rv.z, acc0.z);
    acc0.w = fmaf(xv.w, rv.w, acc0.w);
  }
  float4 pre;
  pre.x = acc0.x + acc1.x;
  pre.y = acc0.y + acc1.y;
  pre.z = acc0.z + acc1.z;
  pre.w = acc0.w + acc1.w;

  // butterfly-reduce across the 4 groups (result lands in ALL lanes)
  pre.x += __shfl_xor(pre.x, 16); pre.x += __shfl_xor(pre.x, 32);
  pre.y += __shfl_xor(pre.y, 16); pre.y += __shfl_xor(pre.y, 32);
  pre.z += __shfl_xor(pre.z, 16); pre.z += __shfl_xor(pre.z, 32);
  pre.w += __shfl_xor(pre.w, 16); pre.w += __shfl_xor(pre.w, 32);

  // transpose float4-per-16lane -> scalar col=lane
  const int srcl = lane >> 2;
  const float t0 = __shfl(pre.x, srcl);
  const float t1 = __shfl(pre.y, srcl);
  const float t2 = __shfl(pre.z, srcl);
  const float t3 = __shfl(pre.w, srcl);
  const float ea = (lane & 2) ? ((lane & 1) ? t3 : t2)
                              : ((lane & 1) ? t1 : t0);

  // self-loop row (precomputed, already * sq_out): coalesced b32
  const float yv = y[(size_t)node * 64 + lane];

  // relu(a)*c == relu(a*c) for c>0: fold norm_in (and norm_out if !FINAL)
  const float scale = FINAL ? nr.z : nr.z * nr.w;
  const float r = fmaxf(fmaf(ea, nr.x, yv) * scale, 0.f);
  if (FINAL) {
    ((float*)xout)[(size_t)node * 64 + lane] = r;
  } else {
    ((__half*)xout)[(size_t)node * 64 + lane] = __float2half_rn(r);
  }
}

extern "C" void kernel_launch(void* const* d_in, const int* in_sizes, int n_in,
                              void* d_out, int out_size, void* d_ws, size_t ws_size,
                              hipStream_t stream) {
  const float* x     = (const float*)d_in[0];
  const float* relw  = (const float*)d_in[1];
  const float* w1    = (const float*)d_in[2];
  const float* w2    = (const float*)d_in[3];
  const int*   src   = (const int*)d_in[4];
  const int*   dst   = (const int*)d_in[5];
  const int*   etype = (const int*)d_in[6];

  const int N = in_sizes[0] / 64;
  const int E = in_sizes[4];
  const int R4 = in_sizes[1] / 4;   // relw float4 count (50*64/4 = 800)

  char* w = (char*)d_ws;
  size_t off = 0;
  auto alloc = [&](size_t bytes) -> void* {
    void* p = w + off;
    off = (off + bytes + 255) & ~(size_t)255;
    return p;
  };
  int*    out_cnt = (int*)alloc((size_t)N * 4);     // zeroed (contiguous with in_cnt)
  int*    in_cnt  = (int*)alloc((size_t)N * 4);
  int*    rowptr  = (int*)alloc((size_t)(N + 1) * 4);   // partial (scan_a output)
  int*    rowfin  = (int*)alloc((size_t)(N + 1) * 4);   // final CSR rowptr
  float4* nrm4    = (float4*)alloc((size_t)N * 16);
  int*    bsums   = (int*)alloc(256 * 4);
  int*    boff    = (int*)alloc(256 * 4);
  int*    rank    = (int*)alloc((size_t)E * 4);     // in-bucket arrival rank
  int*    ce      = (int*)alloc((size_t)E * 4);     // packed src|etype<<20
  uint2*  rwh     = (uint2*)alloc((size_t)R4 * 8);  // relw fp16 packed
  uint2*  xsh     = (uint2*)alloc((size_t)N * 16 * 8);  // fp16 prescaled input
  uint2*  h1h     = (uint2*)alloc((size_t)N * 16 * 8);  // fp16 hidden layer
  float*  y       = (float*)alloc((size_t)N * 64 * 4);  // self-loop rows (fp32)

  // zero the two degree arrays (contiguous in ws)
  hipMemsetAsync(out_cnt, 0, ((char*)rowptr - (char*)out_cnt), stream);

  const int nb = (N + SCAN_BLK - 1) / SCAN_BLK;

  deg_rank_kernel<<<4096, 256, 0, stream>>>(src, dst, out_cnt, in_cnt, rank, E);
  scan_a<<<nb, SCAN_BLK, 0, stream>>>(in_cnt, rowptr + 1, bsums, N);
  scan_b<<<1, 256, 0, stream>>>(bsums, boff, nb);
  scan_c2<<<(N + 255) / 256, 256, 0, stream>>>(rowptr, boff, out_cnt, in_cnt,
                                               rowfin, nrm4, N);
  prescale_h<<<(N * 16 + 255) / 256, 256, 0, stream>>>((const float4*)x, nrm4, xsh, N * 16);
  cvt_relw<<<(R4 + 255) / 256, 256, 0, stream>>>((const float4*)relw, rwh, R4);
  scatter_csr<<<4096, 256, 0, stream>>>(src, dst, etype, rank, rowfin, ce, E);

  const int lblocks = (N + 3) / 4;
  selfloop_kernel<<<4096, 256, 0, stream>>>(xsh, w1, nrm4, y, N);
  layer_kernel<false><<<lblocks, 256, 0, stream>>>(xsh, y, rwh, rowfin, ce, nrm4,
                                                   (void*)h1h, N);
  selfloop_kernel<<<4096, 256, 0, stream>>>(h1h, w2, nrm4, y, N);
  layer_kernel<true><<<lblocks, 256, 0, stream>>>(h1h, y, rwh, rowfin, ce, nrm4,
                                                  d_out, N);
}